// Round 13
// baseline (117.735 us; speedup 1.0000x reference)
//
#include <hip/hip_runtime.h>

// LightGCN extractor, round 13:
//  - build: R8 two-level counting sort (all global writes dense)
//  - fused launches: conv0+count, out_main+out_tail (11 -> 9 dispatches)
//  - k_sort at 1024 threads (halved pass iterations)
//  - gathers: R11's proven 16 rows/block, 4 rows/wave, 16-lane groups, 8B/lane
//  NOTE: float atomicAdd on __shared__ is a slow generic path (~8000cy, R7) - avoid.

#define STU 100000
#define EXER 50000
#define KNOW 123
#define DIM 64
#define N_NODES 150000
#define N_EDGES 1200000
#define NB 8192
#define BR 256                 // rows per bucket
#define NBUCK 586              // ceil(150000/256)
#define PB 256                 // partition blocks
#define EPB 4688               // ceil(N_EDGES/PB)
#define NSB 586                // scan blocks over NBUCK*PB = 150016
#define SCAP 3072              // max edges per bucket (mean 2048)
#define RPB 16                 // rows per gather block
#define RCAP 512               // record staging cap (sum of 16 Poisson(8) ~ 128)
#define CONVB 9375             // conv0 blocks (2.4M float4 / 256)

typedef unsigned short bfu;

__device__ __forceinline__ bfu f2bf(float f) {
    unsigned int u = __float_as_uint(f);
    unsigned int r = (u + 0x7FFFu + ((u >> 16) & 1u)) >> 16;   // RNE
    return (bfu)r;
}
__device__ __forceinline__ float bf2f(bfu h) {
    return __uint_as_float((unsigned int)h << 16);
}

// ---- fused: h0 concat -> bf16 table  |  bucket counts ----
__global__ __launch_bounds__(256) void k_conv_count(const float* __restrict__ stu,
                                                    const float* __restrict__ exer,
                                                    bfu* __restrict__ b0,
                                                    const int* __restrict__ erow,
                                                    int* __restrict__ gcounts) {
    if (blockIdx.x < CONVB) {
        long long i = (long long)blockIdx.x * 256 + threadIdx.x;  // float4 index
        long long n4 = ((long long)N_NODES * DIM) >> 2;
        if (i >= n4) return;
        long long stu4 = ((long long)STU * DIM) >> 2;
        float4 v = (i < stu4) ? ((const float4*)stu)[i]
                              : ((const float4*)exer)[i - stu4];
        ushort4 o;
        o.x = f2bf(v.x); o.y = f2bf(v.y); o.z = f2bf(v.z); o.w = f2bf(v.w);
        ((ushort4*)b0)[i] = o;
    } else {
        __shared__ int cnt[NBUCK];
        int tid = threadIdx.x;
        for (int i = tid; i < NBUCK; i += 256) cnt[i] = 0;
        __syncthreads();
        int b = blockIdx.x - CONVB;
        long long s = (long long)b * EPB;
        long long e = s + EPB; if (e > N_EDGES) e = N_EDGES;
        for (long long k = s + tid; k < e; k += 256)
            atomicAdd(&cnt[__builtin_nontemporal_load(&erow[k]) >> 8], 1);
        __syncthreads();
        for (int i = tid; i < NBUCK; i += 256) gcounts[i * PB + b] = cnt[i];
    }
}

// ---- hierarchical exclusive scan over 150016 ints ----
__global__ void k_scan1(const int* __restrict__ gin, int* __restrict__ gout,
                        int* __restrict__ bsum) {
    __shared__ int s[256];
    int i = blockIdx.x * 256 + threadIdx.x;
    int v = gin[i];
    s[threadIdx.x] = v;
    __syncthreads();
    for (int o = 1; o < 256; o <<= 1) {
        int x = (threadIdx.x >= o) ? s[threadIdx.x - o] : 0;
        __syncthreads();
        s[threadIdx.x] += x;
        __syncthreads();
    }
    gout[i] = s[threadIdx.x] - v;
    if (threadIdx.x == 255) bsum[blockIdx.x] = s[255];
}

__global__ void k_scan2(const int* __restrict__ bsum, int* __restrict__ bsumoff) {
    __shared__ int s[1024];
    int t = threadIdx.x;
    int v = (t < NSB) ? bsum[t] : 0;
    s[t] = v;
    __syncthreads();
    for (int o = 1; o < 1024; o <<= 1) {
        int x = (t >= o) ? s[t - o] : 0;
        __syncthreads();
        s[t] += x;
        __syncthreads();
    }
    if (t < NSB) bsumoff[t] = s[t] - v;
}

__global__ void k_scan3(int* __restrict__ gout, const int* __restrict__ bsumoff,
                        int* __restrict__ boff) {
    int i = blockIdx.x * 256 + threadIdx.x;
    int v = gout[i] + bsumoff[i >> 8];
    gout[i] = v;
    if ((i & 255) == 0) boff[i >> 8] = v;   // PB==256: bucket start
    if (i == 0) boff[NBUCK] = N_EDGES;
}

// ---- place: block-local LDS counting sort by bucket, dense run writes ----
__global__ __launch_bounds__(1024) void k_place(const int* __restrict__ erow,
                                                const int* __restrict__ ecol,
                                                const float* __restrict__ eval,
                                                const int* __restrict__ gscan,
                                                int2* __restrict__ bedge) {
    __shared__ int2 staged[EPB];            // 37504 B
    __shared__ unsigned short sbkt[EPB];    // 9376 B
    __shared__ int lbase[NBUCK];
    __shared__ int lcur[NBUCK];
    __shared__ int gbase[NBUCK];
    __shared__ int stmp[1024];
    int b = blockIdx.x, tid = threadIdx.x;
    for (int i = tid; i < NBUCK; i += 1024) lcur[i] = 0;
    __syncthreads();
    long long s = (long long)b * EPB;
    long long e = s + EPB; if (e > N_EDGES) e = N_EDGES;
    int n = (int)(e - s);
    for (int k = tid; k < n; k += 1024)
        atomicAdd(&lcur[__builtin_nontemporal_load(&erow[s + k]) >> 8], 1);
    __syncthreads();
    int v = (tid < NBUCK) ? lcur[tid] : 0;
    stmp[tid] = v;
    __syncthreads();
    for (int o = 1; o < 1024; o <<= 1) {
        int x = (tid >= o) ? stmp[tid - o] : 0;
        __syncthreads();
        stmp[tid] += x;
        __syncthreads();
    }
    if (tid < NBUCK) { lbase[tid] = stmp[tid] - v; lcur[tid] = stmp[tid] - v; }
    for (int i = tid; i < NBUCK; i += 1024) gbase[i] = gscan[i * PB + b];
    __syncthreads();
    for (int k = tid; k < n; k += 1024) {
        int r = __builtin_nontemporal_load(&erow[s + k]);
        int c = __builtin_nontemporal_load(&ecol[s + k]);
        float vv = __builtin_nontemporal_load(&eval[s + k]);
        int bk = r >> 8;
        int p = atomicAdd(&lcur[bk], 1);
        staged[p] = make_int2((r & 255) | (c << 8), __float_as_int(vv));
        sbkt[p] = (unsigned short)bk;
    }
    __syncthreads();
    for (int t = tid; t < n; t += 1024) {
        int bk = sbkt[t];
        bedge[gbase[bk] + (t - lbase[bk])] = staged[t];
    }
}

// ---- per-bucket LDS counting sort by row -> row-sorted edges + off[] ----
__global__ __launch_bounds__(1024) void k_sort(const int* __restrict__ boff,
                                               const int2* __restrict__ bedge,
                                               int2* __restrict__ sedge,
                                               int* __restrict__ off) {
    __shared__ int2 st[SCAP];      // 24 KB
    __shared__ int2 st2[SCAP];     // 24 KB
    __shared__ int hist[BR];
    __shared__ int cur[BR];
    __shared__ int stmp[1024];     // 4 KB (total ~54 KB)
    int b = blockIdx.x, tid = threadIdx.x;
    int s = boff[b], e = boff[b + 1];
    int n = e - s; if (n > SCAP) n = SCAP;   // statistically unreachable
    if (tid < BR) hist[tid] = 0;
    __syncthreads();
    for (int t = tid; t < n; t += 1024) {
        int2 ev = bedge[s + t];
        st[t] = ev;
        atomicAdd(&hist[ev.x & 255], 1);
    }
    __syncthreads();
    int v = (tid < BR) ? hist[tid] : 0;
    stmp[tid] = v;
    __syncthreads();
    for (int o = 1; o < 1024; o <<= 1) {
        int x = (tid >= o) ? stmp[tid - o] : 0;
        __syncthreads();
        stmp[tid] += x;
        __syncthreads();
    }
    if (tid < BR) {
        int ex = stmp[tid] - v;
        cur[tid] = ex;
        off[b * BR + tid] = s + ex;    // global row offset
    }
    __syncthreads();
    for (int t = tid; t < n; t += 1024) {
        int2 ev = st[t];
        int p = atomicAdd(&cur[ev.x & 255], 1);
        st2[p] = make_int2((unsigned)ev.x >> 8, ev.y);   // (col, valbits)
    }
    __syncthreads();
    for (int t = tid; t < n; t += 1024) sedge[s + t] = st2[t];
}

// ---- gather layer: 16 rows/block, records LDS-staged, 4 rows/wave ----
__global__ __launch_bounds__(256) void k_gather16(const int* __restrict__ off,
                                                  const int2* __restrict__ sedge,
                                                  const bfu* __restrict__ h,
                                                  bfu* __restrict__ out) {
    __shared__ int2 rec[RCAP];
    __shared__ int soff[RPB + 1];
    int tid = threadIdx.x;
    int base = blockIdx.x * RPB;                 // 9375 blocks x 16 rows = 150000
    if (tid <= RPB) soff[tid] = off[base + tid];
    __syncthreads();
    int s0 = soff[0];
    int n = soff[RPB] - s0; if (n > RCAP) n = RCAP;   // unreachable
    for (int i = tid; i < n; i += 256) rec[i] = sedge[s0 + i];   // dense coalesced
    __syncthreads();

    int wv = tid >> 6, grp = (tid >> 4) & 3, l16 = tid & 15;
    int lr = wv * 4 + grp;                        // local row 0..15
    int rs = soff[lr] - s0, re = soff[lr + 1] - s0;
    const uint2* h2 = (const uint2*)h;            // row = 16 x uint2 (128B)
    float a0 = 0.f, a1 = 0.f, a2 = 0.f, a3 = 0.f;
    for (int k = rs; k < re; k += 8) {
        int2 ev[8]; float wg[8];
#pragma unroll
        for (int q = 0; q < 8; q++) {
            int idx = (k + q < re) ? (k + q) : rs;
            ev[q] = rec[idx];
            wg[q] = (k + q < re) ? __int_as_float(ev[q].y) : 0.f;
        }
        uint2 hv[8];
#pragma unroll
        for (int q = 0; q < 8; q++) hv[q] = h2[(size_t)ev[q].x * 16 + l16];
#pragma unroll
        for (int q = 0; q < 8; q++) {
            a0 += wg[q] * __uint_as_float(hv[q].x << 16);
            a1 += wg[q] * __uint_as_float(hv[q].x & 0xffff0000u);
            a2 += wg[q] * __uint_as_float(hv[q].y << 16);
            a3 += wg[q] * __uint_as_float(hv[q].y & 0xffff0000u);
        }
    }
    uint2 o;
    o.x = (unsigned)f2bf(a0) | ((unsigned)f2bf(a1) << 16);
    o.y = (unsigned)f2bf(a2) | ((unsigned)f2bf(a3) << 16);
    ((uint2*)out)[(size_t)(base + lr) * 16 + l16] = o;
}

// ---- fused outputs: layer-3 gather over B2 + disc/know tails ----
// out layout: [0,524288) student_ts | [524288,1048576) diff_ts
//             [1048576,1056768) disc | [1056768,1064640) know
__global__ void k_out(const int* __restrict__ sid, const int* __restrict__ eid,
                      const int* __restrict__ off, const int2* __restrict__ sedge,
                      const float* __restrict__ stu, const float* __restrict__ exer,
                      const bfu* __restrict__ B1, const bfu* __restrict__ B2,
                      const float* __restrict__ disc, const float* __restrict__ know,
                      float* __restrict__ out) {
    if (blockIdx.x >= 4096) {
        int i = (blockIdx.x - 4096) * 256 + threadIdx.x;
        if (i < NB) out[1048576 + i] = disc[eid[i]];
        else if (i < NB + KNOW * DIM) out[1056768 + (i - NB)] = know[i - NB];
        return;
    }
    int w = (blockIdx.x * 256 + threadIdx.x) >> 6;
    int lane = threadIdx.x & 63;
    int wu = __builtin_amdgcn_readfirstlane(w);
    int r;
    long long obase;
    if (wu < NB) { r = sid[wu];            obase = (long long)wu * 64; }
    else         { r = STU + eid[wu - NB]; obase = 524288 + (long long)(wu - NB) * 64; }
    int ru = __builtin_amdgcn_readfirstlane(r);
    long long rb = (long long)ru * 64 + lane;
    float h0 = (ru < STU) ? stu[rb] : exer[rb - (long long)STU * 64];
    float ssum = h0 + bf2f(B1[rb]) + bf2f(B2[rb]);
    int st = off[ru], en = off[ru + 1];
    float g = 0.f;
    int k = st;
    for (; k + 8 <= en; k += 8) {
        int2 ev[8];
#pragma unroll
        for (int j = 0; j < 8; j++) ev[j] = sedge[k + j];
        float a[8];
#pragma unroll
        for (int j = 0; j < 8; j++) a[j] = bf2f(B2[(size_t)ev[j].x * DIM + lane]);
#pragma unroll
        for (int j = 0; j < 8; j++) g += __int_as_float(ev[j].y) * a[j];
    }
    for (; k < en; k++) {
        int2 ev = sedge[k];
        g += __int_as_float(ev.y) * bf2f(B2[(size_t)ev.x * DIM + lane]);
    }
    out[obase + lane] = 0.25f * (ssum + g);
}

extern "C" void kernel_launch(void* const* d_in, const int* in_sizes, int n_in,
                              void* d_out, int out_size, void* d_ws, size_t ws_size,
                              hipStream_t stream) {
    const int*   sid  = (const int*)d_in[0];
    const int*   eid  = (const int*)d_in[1];
    const int*   erow = (const int*)d_in[3];
    const int*   ecol = (const int*)d_in[4];
    const float* eval = (const float*)d_in[5];
    const float* stu  = (const float*)d_in[6];
    const float* exer = (const float*)d_in[7];
    const float* disc = (const float*)d_in[8];
    const float* know = (const float*)d_in[9];
    float* out = (float*)d_out;

    char* ws = (char*)d_ws;
    bfu*  B0      = (bfu*) (ws);                          // 19,200,000
    bfu*  B1      = (bfu*) (ws + 19200000);               // 19,200,000
    bfu*  B2      = (bfu*) (ws + 38400000);               // 19,200,000
    int2* bedge   = (int2*)(ws + 57600000);               // 9,600,000 (bucket-sorted)
    int2* sedge   = (int2*)(ws + 67200000);               // 9,600,000 (row-sorted)
    int*  gcounts = (int*) (ws + 76800000);               // 600,064
    int*  gscan   = (int*) (ws + 77400064);               // 600,064
    int*  bsum    = (int*) (ws + 78000128);               // 2,560
    int*  bsumoff = (int*) (ws + 78002688);               // 2,560
    int*  boff    = (int*) (ws + 78005248);               // 2,348
    int*  off     = (int*) (ws + 78007596);               // 600,064 (ends ~78.6 MB)

    const int BLK = 256;
    int gatherGrid = N_NODES / RPB;                       // 9375 blocks

    // fused conv0 + bucket counts
    k_conv_count<<<CONVB + PB, BLK, 0, stream>>>(stu, exer, B0, erow, gcounts);

    // scans + place + row sort (all writes dense)
    k_scan1<<<NSB, 256, 0, stream>>>(gcounts, gscan, bsum);
    k_scan2<<<1, 1024, 0, stream>>>(bsum, bsumoff);
    k_scan3<<<NSB, 256, 0, stream>>>(gscan, bsumoff, boff);
    k_place<<<PB, 1024, 0, stream>>>(erow, ecol, eval, gscan, bedge);
    k_sort <<<NBUCK, 1024, 0, stream>>>(boff, bedge, sedge, off);

    // layers 1,2
    k_gather16<<<gatherGrid, BLK, 0, stream>>>(off, sedge, B0, B1);
    k_gather16<<<gatherGrid, BLK, 0, stream>>>(off, sedge, B1, B2);

    // fused outputs (layer 3 + tails)
    k_out<<<4096 + 63, BLK, 0, stream>>>(sid, eid, off, sedge, stu, exer, B1, B2,
                                         disc, know, out);
}

// Round 14
// 109.342 us; speedup vs baseline: 1.0768x; 1.0768x over previous
//
#include <hip/hip_runtime.h>

// LightGCN extractor, round 14: R11 base (proven 112us), scan3 folded away.
//  - build: two-level counting sort, all global writes dense lane-consecutive
//  - PB == 256 == scan width  =>  bucket base = bsumoff[b]; k_place/k_sort
//    apply gscan + bsumoff directly (k_scan3 + boff deleted)
//  - gathers: 16 rows/block, records LDS-staged, 4 rows/wave, 16-lane groups
//  - layer 3 fused into output kernel
//  NOTE: float atomicAdd on __shared__ is a slow generic path (~8000cy, R7) - avoid.
//  NOTE: scatter stores only merge in the wave coalescer at issue time; L2 never
//        merges separately-issued stores (R1-R6 evidence) - hence LDS-staged
//        dense write-out everywhere.

#define STU 100000
#define EXER 50000
#define KNOW 123
#define DIM 64
#define N_NODES 150000
#define N_EDGES 1200000
#define NB 8192
#define BR 256                 // rows per bucket
#define NBUCK 586              // ceil(150000/256)
#define PB 256                 // partition blocks (== scan width, load-bearing)
#define EPB 4688               // ceil(N_EDGES/PB)
#define NSB 586                // scan blocks over NBUCK*PB = 150016
#define SCAP 3072              // max edges per bucket (mean 2048)
#define RPB 16                 // rows per gather block
#define RCAP 512               // record staging cap (sum of 16 Poisson(8) ~ 128)

typedef unsigned short bfu;

__device__ __forceinline__ bfu f2bf(float f) {
    unsigned int u = __float_as_uint(f);
    unsigned int r = (u + 0x7FFFu + ((u >> 16) & 1u)) >> 16;   // RNE
    return (bfu)r;
}
__device__ __forceinline__ float bf2f(bfu h) {
    return __uint_as_float((unsigned int)h << 16);
}

// ---- h0 concat -> bf16 table ----
__global__ void k_conv0(const float* __restrict__ stu, const float* __restrict__ exer,
                        bfu* __restrict__ b0) {
    long long i = (long long)blockIdx.x * blockDim.x + threadIdx.x;  // float4 index
    long long n4 = ((long long)N_NODES * DIM) >> 2;
    if (i >= n4) return;
    long long stu4 = ((long long)STU * DIM) >> 2;
    float4 v = (i < stu4) ? ((const float4*)stu)[i]
                          : ((const float4*)exer)[i - stu4];
    ushort4 o;
    o.x = f2bf(v.x); o.y = f2bf(v.y); o.z = f2bf(v.z); o.w = f2bf(v.w);
    ((ushort4*)b0)[i] = o;
}

// ---- bucket counts: gcounts[bucket*PB + block] ----
__global__ __launch_bounds__(1024) void k_count(const int* __restrict__ erow,
                                                int* __restrict__ gcounts) {
    __shared__ int cnt[NBUCK];
    for (int i = threadIdx.x; i < NBUCK; i += 1024) cnt[i] = 0;
    __syncthreads();
    int b = blockIdx.x;
    long long s = (long long)b * EPB;
    long long e = s + EPB; if (e > N_EDGES) e = N_EDGES;
    for (long long k = s + threadIdx.x; k < e; k += 1024)
        atomicAdd(&cnt[__builtin_nontemporal_load(&erow[k]) >> 8], 1);
    __syncthreads();
    for (int i = threadIdx.x; i < NBUCK; i += 1024) gcounts[i * PB + b] = cnt[i];
}

// ---- scan level 1: per-bucket exclusive scan of the 256 partition counts ----
__global__ void k_scan1(const int* __restrict__ gin, int* __restrict__ gout,
                        int* __restrict__ bsum) {
    __shared__ int s[256];
    int i = blockIdx.x * 256 + threadIdx.x;
    int v = gin[i];
    s[threadIdx.x] = v;
    __syncthreads();
    for (int o = 1; o < 256; o <<= 1) {
        int x = (threadIdx.x >= o) ? s[threadIdx.x - o] : 0;
        __syncthreads();
        s[threadIdx.x] += x;
        __syncthreads();
    }
    gout[i] = s[threadIdx.x] - v;
    if (threadIdx.x == 255) bsum[blockIdx.x] = s[255];
}

// ---- scan level 2: exclusive scan over bucket totals (+ sentinel) ----
__global__ void k_scan2(const int* __restrict__ bsum, int* __restrict__ bsumoff) {
    __shared__ int s[1024];
    int t = threadIdx.x;
    int v = (t < NSB) ? bsum[t] : 0;
    s[t] = v;
    __syncthreads();
    for (int o = 1; o < 1024; o <<= 1) {
        int x = (t >= o) ? s[t - o] : 0;
        __syncthreads();
        s[t] += x;
        __syncthreads();
    }
    if (t < NSB) bsumoff[t] = s[t] - v;
    if (t == NSB - 1) bsumoff[NSB] = s[t];   // == N_EDGES sentinel
}

// ---- place: block-local LDS counting sort by bucket, dense run writes ----
__global__ __launch_bounds__(1024) void k_place(const int* __restrict__ erow,
                                                const int* __restrict__ ecol,
                                                const float* __restrict__ eval,
                                                const int* __restrict__ gscan,
                                                const int* __restrict__ bsumoff,
                                                int2* __restrict__ bedge) {
    __shared__ int2 staged[EPB];            // 37504 B
    __shared__ unsigned short sbkt[EPB];    // 9376 B
    __shared__ int lbase[NBUCK];
    __shared__ int lcur[NBUCK];
    __shared__ int gbase[NBUCK];
    __shared__ int stmp[1024];
    int b = blockIdx.x, tid = threadIdx.x;
    for (int i = tid; i < NBUCK; i += 1024) lcur[i] = 0;
    __syncthreads();
    long long s = (long long)b * EPB;
    long long e = s + EPB; if (e > N_EDGES) e = N_EDGES;
    int n = (int)(e - s);
    for (int k = tid; k < n; k += 1024)
        atomicAdd(&lcur[__builtin_nontemporal_load(&erow[s + k]) >> 8], 1);
    __syncthreads();
    int v = (tid < NBUCK) ? lcur[tid] : 0;
    stmp[tid] = v;
    __syncthreads();
    for (int o = 1; o < 1024; o <<= 1) {
        int x = (tid >= o) ? stmp[tid - o] : 0;
        __syncthreads();
        stmp[tid] += x;
        __syncthreads();
    }
    if (tid < NBUCK) { lbase[tid] = stmp[tid] - v; lcur[tid] = stmp[tid] - v; }
    for (int i = tid; i < NBUCK; i += 1024)
        gbase[i] = gscan[i * PB + b] + bsumoff[i];          // scan3 folded in
    __syncthreads();
    for (int k = tid; k < n; k += 1024) {
        int r = __builtin_nontemporal_load(&erow[s + k]);
        int c = __builtin_nontemporal_load(&ecol[s + k]);
        float vv = __builtin_nontemporal_load(&eval[s + k]);
        int bk = r >> 8;
        int p = atomicAdd(&lcur[bk], 1);
        staged[p] = make_int2((r & 255) | (c << 8), __float_as_int(vv));
        sbkt[p] = (unsigned short)bk;
    }
    __syncthreads();
    for (int t = tid; t < n; t += 1024) {
        int bk = sbkt[t];
        bedge[gbase[bk] + (t - lbase[bk])] = staged[t];
    }
}

// ---- per-bucket LDS counting sort by row -> row-sorted edges + off[] ----
__global__ __launch_bounds__(512) void k_sort(const int* __restrict__ bsumoff,
                                              const int2* __restrict__ bedge,
                                              int2* __restrict__ sedge,
                                              int* __restrict__ off) {
    __shared__ int2 st[SCAP];      // 24 KB
    __shared__ int2 st2[SCAP];     // 24 KB
    __shared__ int hist[BR];
    __shared__ int cur[BR];
    __shared__ int stmp[512];
    int b = blockIdx.x, tid = threadIdx.x;
    int s = bsumoff[b], e = bsumoff[b + 1];    // bucket bounds (scan3 folded in)
    int n = e - s; if (n > SCAP) n = SCAP;     // statistically unreachable
    for (int i = tid; i < BR; i += 512) hist[i] = 0;
    __syncthreads();
    for (int t = tid; t < n; t += 512) {
        int2 ev = bedge[s + t];
        st[t] = ev;
        atomicAdd(&hist[ev.x & 255], 1);
    }
    __syncthreads();
    int v = (tid < BR) ? hist[tid] : 0;
    stmp[tid] = v;
    __syncthreads();
    for (int o = 1; o < 512; o <<= 1) {
        int x = (tid >= o) ? stmp[tid - o] : 0;
        __syncthreads();
        stmp[tid] += x;
        __syncthreads();
    }
    if (tid < BR) {
        int ex = stmp[tid] - v;
        cur[tid] = ex;
        off[b * BR + tid] = s + ex;    // global row offset
    }
    __syncthreads();
    for (int t = tid; t < n; t += 512) {
        int2 ev = st[t];
        int p = atomicAdd(&cur[ev.x & 255], 1);
        st2[p] = make_int2((unsigned)ev.x >> 8, ev.y);   // (col, valbits)
    }
    __syncthreads();
    for (int t = tid; t < n; t += 512) sedge[s + t] = st2[t];
}

// ---- gather layer: 16 rows/block, records LDS-staged, 4 rows/wave ----
__global__ __launch_bounds__(256) void k_gather16(const int* __restrict__ off,
                                                  const int2* __restrict__ sedge,
                                                  const bfu* __restrict__ h,
                                                  bfu* __restrict__ out) {
    __shared__ int2 rec[RCAP];
    __shared__ int soff[RPB + 1];
    int tid = threadIdx.x;
    int base = blockIdx.x * RPB;                 // 9375 blocks x 16 rows = 150000
    if (tid <= RPB) soff[tid] = off[base + tid];
    __syncthreads();
    int s0 = soff[0];
    int n = soff[RPB] - s0; if (n > RCAP) n = RCAP;   // unreachable
    for (int i = tid; i < n; i += 256) rec[i] = sedge[s0 + i];   // dense coalesced
    __syncthreads();

    int wv = tid >> 6, grp = (tid >> 4) & 3, l16 = tid & 15;
    int lr = wv * 4 + grp;                        // local row 0..15
    int rs = soff[lr] - s0, re = soff[lr + 1] - s0;
    const uint2* h2 = (const uint2*)h;            // row = 16 x uint2 (128B)
    float a0 = 0.f, a1 = 0.f, a2 = 0.f, a3 = 0.f;
    for (int k = rs; k < re; k += 8) {
        int2 ev[8]; float wg[8];
#pragma unroll
        for (int q = 0; q < 8; q++) {
            int idx = (k + q < re) ? (k + q) : rs;
            ev[q] = rec[idx];
            wg[q] = (k + q < re) ? __int_as_float(ev[q].y) : 0.f;
        }
        uint2 hv[8];
#pragma unroll
        for (int q = 0; q < 8; q++) hv[q] = h2[(size_t)ev[q].x * 16 + l16];
#pragma unroll
        for (int q = 0; q < 8; q++) {
            a0 += wg[q] * __uint_as_float(hv[q].x << 16);
            a1 += wg[q] * __uint_as_float(hv[q].x & 0xffff0000u);
            a2 += wg[q] * __uint_as_float(hv[q].y << 16);
            a3 += wg[q] * __uint_as_float(hv[q].y & 0xffff0000u);
        }
    }
    uint2 o;
    o.x = (unsigned)f2bf(a0) | ((unsigned)f2bf(a1) << 16);
    o.y = (unsigned)f2bf(a2) | ((unsigned)f2bf(a3) << 16);
    ((uint2*)out)[(size_t)(base + lr) * 16 + l16] = o;
}

// ---- outputs: layer-3 gather over B2 fused, only the 16K needed rows ----
// out layout: [0,524288) student_ts | [524288,1048576) diff_ts
//             [1048576,1056768) disc | [1056768,1064640) know
__global__ void k_out_main(const int* __restrict__ sid, const int* __restrict__ eid,
                           const int* __restrict__ off, const int2* __restrict__ sedge,
                           const float* __restrict__ stu, const float* __restrict__ exer,
                           const bfu* __restrict__ B1, const bfu* __restrict__ B2,
                           float* __restrict__ out) {
    int w = (blockIdx.x * blockDim.x + threadIdx.x) >> 6;
    int lane = threadIdx.x & 63;
    if (w >= 2 * NB) return;
    int wu = __builtin_amdgcn_readfirstlane(w);
    int r;
    long long obase;
    if (wu < NB) { r = sid[wu];            obase = (long long)wu * 64; }
    else         { r = STU + eid[wu - NB]; obase = 524288 + (long long)(wu - NB) * 64; }
    int ru = __builtin_amdgcn_readfirstlane(r);
    long long rb = (long long)ru * 64 + lane;
    float h0 = (ru < STU) ? stu[rb] : exer[rb - (long long)STU * 64];
    float ssum = h0 + bf2f(B1[rb]) + bf2f(B2[rb]);
    int st = off[ru], en = off[ru + 1];
    float g = 0.f;
    int k = st;
    for (; k + 8 <= en; k += 8) {
        int2 ev[8];
#pragma unroll
        for (int j = 0; j < 8; j++) ev[j] = sedge[k + j];
        float a[8];
#pragma unroll
        for (int j = 0; j < 8; j++) a[j] = bf2f(B2[(size_t)ev[j].x * DIM + lane]);
#pragma unroll
        for (int j = 0; j < 8; j++) g += __int_as_float(ev[j].y) * a[j];
    }
    for (; k < en; k++) {
        int2 ev = sedge[k];
        g += __int_as_float(ev.y) * bf2f(B2[(size_t)ev.x * DIM + lane]);
    }
    out[obase + lane] = 0.25f * (ssum + g);
}

__global__ void k_out_tail(const int* __restrict__ eid, const float* __restrict__ disc,
                           const float* __restrict__ know, float* __restrict__ out) {
    int i = blockIdx.x * blockDim.x + threadIdx.x;
    if (i < NB) out[1048576 + i] = disc[eid[i]];
    else if (i < NB + KNOW * DIM) out[1056768 + (i - NB)] = know[i - NB];
}

extern "C" void kernel_launch(void* const* d_in, const int* in_sizes, int n_in,
                              void* d_out, int out_size, void* d_ws, size_t ws_size,
                              hipStream_t stream) {
    const int*   sid  = (const int*)d_in[0];
    const int*   eid  = (const int*)d_in[1];
    const int*   erow = (const int*)d_in[3];
    const int*   ecol = (const int*)d_in[4];
    const float* eval = (const float*)d_in[5];
    const float* stu  = (const float*)d_in[6];
    const float* exer = (const float*)d_in[7];
    const float* disc = (const float*)d_in[8];
    const float* know = (const float*)d_in[9];
    float* out = (float*)d_out;

    char* ws = (char*)d_ws;
    bfu*  B0      = (bfu*) (ws);                          // 19,200,000
    bfu*  B1      = (bfu*) (ws + 19200000);               // 19,200,000
    bfu*  B2      = (bfu*) (ws + 38400000);               // 19,200,000
    int2* bedge   = (int2*)(ws + 57600000);               // 9,600,000 (bucket-sorted)
    int2* sedge   = (int2*)(ws + 67200000);               // 9,600,000 (row-sorted)
    int*  gcounts = (int*) (ws + 76800000);               // 600,064
    int*  gscan   = (int*) (ws + 77400064);               // 600,064
    int*  bsum    = (int*) (ws + 78000128);               // 2,560
    int*  bsumoff = (int*) (ws + 78002688);               // 2,560 (587 ints + pad)
    int*  off     = (int*) (ws + 78005248);               // 600,064 (ends ~78.6 MB)

    const int BLK = 256;
    long long n4 = ((long long)N_NODES * DIM) >> 2;
    int convGrid = (int)((n4 + BLK - 1) / BLK);
    int gatherGrid = N_NODES / RPB;                       // 9375 blocks
    int outMainGrid = (2 * NB * 64) / BLK;
    int outTailGrid = (NB + KNOW * DIM + BLK - 1) / BLK;

    // h0 -> bf16 table
    k_conv0<<<convGrid, BLK, 0, stream>>>(stu, exer, B0);

    // two-level counting sort (all writes dense); scan3 folded into place/sort
    k_count<<<PB, 1024, 0, stream>>>(erow, gcounts);
    k_scan1<<<NSB, 256, 0, stream>>>(gcounts, gscan, bsum);
    k_scan2<<<1, 1024, 0, stream>>>(bsum, bsumoff);
    k_place<<<PB, 1024, 0, stream>>>(erow, ecol, eval, gscan, bsumoff, bedge);
    k_sort <<<NBUCK, 512, 0, stream>>>(bsumoff, bedge, sedge, off);

    // layers 1,2
    k_gather16<<<gatherGrid, BLK, 0, stream>>>(off, sedge, B0, B1);
    k_gather16<<<gatherGrid, BLK, 0, stream>>>(off, sedge, B1, B2);

    // layer 3 fused into outputs
    k_out_main<<<outMainGrid, BLK, 0, stream>>>(sid, eid, off, sedge, stu, exer, B1, B2, out);
    k_out_tail<<<outTailGrid, BLK, 0, stream>>>(eid, disc, know, out);
}

// Round 15
// 104.888 us; speedup vs baseline: 1.1225x; 1.0425x over previous
//
#include <hip/hip_runtime.h>

// LightGCN extractor, round 15: R14 base + output kernel rebuilt as
// 2-rows-per-wave (half-wave split, R10 recipe) with fused disc/know tail.
//  - build: two-level counting sort, all global writes dense lane-consecutive
//  - gathers: 16 rows/block, records LDS-staged, 4 rows/wave, 16-lane groups
//  NOTE: float atomicAdd on __shared__ is a slow generic path (~8000cy, R7) - avoid.
//  NOTE: scatter stores only merge in the wave coalescer at issue time; L2 never
//        merges separately-issued stores (R1-R6 evidence) - LDS-staged dense
//        write-out everywhere.

#define STU 100000
#define EXER 50000
#define KNOW 123
#define DIM 64
#define N_NODES 150000
#define N_EDGES 1200000
#define NB 8192
#define BR 256                 // rows per bucket
#define NBUCK 586              // ceil(150000/256)
#define PB 256                 // partition blocks (== scan width, load-bearing)
#define EPB 4688               // ceil(N_EDGES/PB)
#define NSB 586                // scan blocks over NBUCK*PB = 150016
#define SCAP 3072              // max edges per bucket (mean 2048)
#define RPB 16                 // rows per gather block
#define RCAP 512               // record staging cap (sum of 16 Poisson(8) ~ 128)
#define OUTMAIN 2048           // out kernel: main blocks (8192 waves, 2 rows each)

typedef unsigned short bfu;

__device__ __forceinline__ bfu f2bf(float f) {
    unsigned int u = __float_as_uint(f);
    unsigned int r = (u + 0x7FFFu + ((u >> 16) & 1u)) >> 16;   // RNE
    return (bfu)r;
}
__device__ __forceinline__ float bf2f(bfu h) {
    return __uint_as_float((unsigned int)h << 16);
}

// ---- h0 concat -> bf16 table ----
__global__ void k_conv0(const float* __restrict__ stu, const float* __restrict__ exer,
                        bfu* __restrict__ b0) {
    long long i = (long long)blockIdx.x * blockDim.x + threadIdx.x;  // float4 index
    long long n4 = ((long long)N_NODES * DIM) >> 2;
    if (i >= n4) return;
    long long stu4 = ((long long)STU * DIM) >> 2;
    float4 v = (i < stu4) ? ((const float4*)stu)[i]
                          : ((const float4*)exer)[i - stu4];
    ushort4 o;
    o.x = f2bf(v.x); o.y = f2bf(v.y); o.z = f2bf(v.z); o.w = f2bf(v.w);
    ((ushort4*)b0)[i] = o;
}

// ---- bucket counts: gcounts[bucket*PB + block] ----
__global__ __launch_bounds__(1024) void k_count(const int* __restrict__ erow,
                                                int* __restrict__ gcounts) {
    __shared__ int cnt[NBUCK];
    for (int i = threadIdx.x; i < NBUCK; i += 1024) cnt[i] = 0;
    __syncthreads();
    int b = blockIdx.x;
    long long s = (long long)b * EPB;
    long long e = s + EPB; if (e > N_EDGES) e = N_EDGES;
    for (long long k = s + threadIdx.x; k < e; k += 1024)
        atomicAdd(&cnt[__builtin_nontemporal_load(&erow[k]) >> 8], 1);
    __syncthreads();
    for (int i = threadIdx.x; i < NBUCK; i += 1024) gcounts[i * PB + b] = cnt[i];
}

// ---- scan level 1: per-bucket exclusive scan of the 256 partition counts ----
__global__ void k_scan1(const int* __restrict__ gin, int* __restrict__ gout,
                        int* __restrict__ bsum) {
    __shared__ int s[256];
    int i = blockIdx.x * 256 + threadIdx.x;
    int v = gin[i];
    s[threadIdx.x] = v;
    __syncthreads();
    for (int o = 1; o < 256; o <<= 1) {
        int x = (threadIdx.x >= o) ? s[threadIdx.x - o] : 0;
        __syncthreads();
        s[threadIdx.x] += x;
        __syncthreads();
    }
    gout[i] = s[threadIdx.x] - v;
    if (threadIdx.x == 255) bsum[blockIdx.x] = s[255];
}

// ---- scan level 2: exclusive scan over bucket totals (+ sentinel) ----
__global__ void k_scan2(const int* __restrict__ bsum, int* __restrict__ bsumoff) {
    __shared__ int s[1024];
    int t = threadIdx.x;
    int v = (t < NSB) ? bsum[t] : 0;
    s[t] = v;
    __syncthreads();
    for (int o = 1; o < 1024; o <<= 1) {
        int x = (t >= o) ? s[t - o] : 0;
        __syncthreads();
        s[t] += x;
        __syncthreads();
    }
    if (t < NSB) bsumoff[t] = s[t] - v;
    if (t == NSB - 1) bsumoff[NSB] = s[t];   // == N_EDGES sentinel
}

// ---- place: block-local LDS counting sort by bucket, dense run writes ----
__global__ __launch_bounds__(1024) void k_place(const int* __restrict__ erow,
                                                const int* __restrict__ ecol,
                                                const float* __restrict__ eval,
                                                const int* __restrict__ gscan,
                                                const int* __restrict__ bsumoff,
                                                int2* __restrict__ bedge) {
    __shared__ int2 staged[EPB];            // 37504 B
    __shared__ unsigned short sbkt[EPB];    // 9376 B
    __shared__ int lbase[NBUCK];
    __shared__ int lcur[NBUCK];
    __shared__ int gbase[NBUCK];
    __shared__ int stmp[1024];
    int b = blockIdx.x, tid = threadIdx.x;
    for (int i = tid; i < NBUCK; i += 1024) lcur[i] = 0;
    __syncthreads();
    long long s = (long long)b * EPB;
    long long e = s + EPB; if (e > N_EDGES) e = N_EDGES;
    int n = (int)(e - s);
    for (int k = tid; k < n; k += 1024)
        atomicAdd(&lcur[__builtin_nontemporal_load(&erow[s + k]) >> 8], 1);
    __syncthreads();
    int v = (tid < NBUCK) ? lcur[tid] : 0;
    stmp[tid] = v;
    __syncthreads();
    for (int o = 1; o < 1024; o <<= 1) {
        int x = (tid >= o) ? stmp[tid - o] : 0;
        __syncthreads();
        stmp[tid] += x;
        __syncthreads();
    }
    if (tid < NBUCK) { lbase[tid] = stmp[tid] - v; lcur[tid] = stmp[tid] - v; }
    for (int i = tid; i < NBUCK; i += 1024)
        gbase[i] = gscan[i * PB + b] + bsumoff[i];          // scan3 folded in
    __syncthreads();
    for (int k = tid; k < n; k += 1024) {
        int r = __builtin_nontemporal_load(&erow[s + k]);
        int c = __builtin_nontemporal_load(&ecol[s + k]);
        float vv = __builtin_nontemporal_load(&eval[s + k]);
        int bk = r >> 8;
        int p = atomicAdd(&lcur[bk], 1);
        staged[p] = make_int2((r & 255) | (c << 8), __float_as_int(vv));
        sbkt[p] = (unsigned short)bk;
    }
    __syncthreads();
    for (int t = tid; t < n; t += 1024) {
        int bk = sbkt[t];
        bedge[gbase[bk] + (t - lbase[bk])] = staged[t];
    }
}

// ---- per-bucket LDS counting sort by row -> row-sorted edges + off[] ----
__global__ __launch_bounds__(512) void k_sort(const int* __restrict__ bsumoff,
                                              const int2* __restrict__ bedge,
                                              int2* __restrict__ sedge,
                                              int* __restrict__ off) {
    __shared__ int2 st[SCAP];      // 24 KB
    __shared__ int2 st2[SCAP];     // 24 KB
    __shared__ int hist[BR];
    __shared__ int cur[BR];
    __shared__ int stmp[512];
    int b = blockIdx.x, tid = threadIdx.x;
    int s = bsumoff[b], e = bsumoff[b + 1];    // bucket bounds
    int n = e - s; if (n > SCAP) n = SCAP;     // statistically unreachable
    for (int i = tid; i < BR; i += 512) hist[i] = 0;
    __syncthreads();
    for (int t = tid; t < n; t += 512) {
        int2 ev = bedge[s + t];
        st[t] = ev;
        atomicAdd(&hist[ev.x & 255], 1);
    }
    __syncthreads();
    int v = (tid < BR) ? hist[tid] : 0;
    stmp[tid] = v;
    __syncthreads();
    for (int o = 1; o < 512; o <<= 1) {
        int x = (tid >= o) ? stmp[tid - o] : 0;
        __syncthreads();
        stmp[tid] += x;
        __syncthreads();
    }
    if (tid < BR) {
        int ex = stmp[tid] - v;
        cur[tid] = ex;
        off[b * BR + tid] = s + ex;    // global row offset
    }
    __syncthreads();
    for (int t = tid; t < n; t += 512) {
        int2 ev = st[t];
        int p = atomicAdd(&cur[ev.x & 255], 1);
        st2[p] = make_int2((unsigned)ev.x >> 8, ev.y);   // (col, valbits)
    }
    __syncthreads();
    for (int t = tid; t < n; t += 512) sedge[s + t] = st2[t];
}

// ---- gather layer: 16 rows/block, records LDS-staged, 4 rows/wave ----
__global__ __launch_bounds__(256) void k_gather16(const int* __restrict__ off,
                                                  const int2* __restrict__ sedge,
                                                  const bfu* __restrict__ h,
                                                  bfu* __restrict__ out) {
    __shared__ int2 rec[RCAP];
    __shared__ int soff[RPB + 1];
    int tid = threadIdx.x;
    int base = blockIdx.x * RPB;                 // 9375 blocks x 16 rows = 150000
    if (tid <= RPB) soff[tid] = off[base + tid];
    __syncthreads();
    int s0 = soff[0];
    int n = soff[RPB] - s0; if (n > RCAP) n = RCAP;   // unreachable
    for (int i = tid; i < n; i += 256) rec[i] = sedge[s0 + i];   // dense coalesced
    __syncthreads();

    int wv = tid >> 6, grp = (tid >> 4) & 3, l16 = tid & 15;
    int lr = wv * 4 + grp;                        // local row 0..15
    int rs = soff[lr] - s0, re = soff[lr + 1] - s0;
    const uint2* h2 = (const uint2*)h;            // row = 16 x uint2 (128B)
    float a0 = 0.f, a1 = 0.f, a2 = 0.f, a3 = 0.f;
    for (int k = rs; k < re; k += 8) {
        int2 ev[8]; float wg[8];
#pragma unroll
        for (int q = 0; q < 8; q++) {
            int idx = (k + q < re) ? (k + q) : rs;
            ev[q] = rec[idx];
            wg[q] = (k + q < re) ? __int_as_float(ev[q].y) : 0.f;
        }
        uint2 hv[8];
#pragma unroll
        for (int q = 0; q < 8; q++) hv[q] = h2[(size_t)ev[q].x * 16 + l16];
#pragma unroll
        for (int q = 0; q < 8; q++) {
            a0 += wg[q] * __uint_as_float(hv[q].x << 16);
            a1 += wg[q] * __uint_as_float(hv[q].x & 0xffff0000u);
            a2 += wg[q] * __uint_as_float(hv[q].y << 16);
            a3 += wg[q] * __uint_as_float(hv[q].y & 0xffff0000u);
        }
    }
    uint2 o;
    o.x = (unsigned)f2bf(a0) | ((unsigned)f2bf(a1) << 16);
    o.y = (unsigned)f2bf(a2) | ((unsigned)f2bf(a3) << 16);
    ((uint2*)out)[(size_t)(base + lr) * 16 + l16] = o;
}

// ---- fused outputs: layer-3 gather, 2 rows/wave (half-wave split) + tails ----
// out layout: [0,524288) student_ts | [524288,1048576) diff_ts
//             [1048576,1056768) disc | [1056768,1064640) know
__global__ __launch_bounds__(256) void k_out(const int* __restrict__ sid,
                                             const int* __restrict__ eid,
                                             const int* __restrict__ off,
                                             const int2* __restrict__ sedge,
                                             const float* __restrict__ stu,
                                             const float* __restrict__ exer,
                                             const bfu* __restrict__ B1,
                                             const bfu* __restrict__ B2,
                                             const float* __restrict__ disc,
                                             const float* __restrict__ know,
                                             float* __restrict__ out) {
    if (blockIdx.x >= OUTMAIN) {
        int i = (blockIdx.x - OUTMAIN) * 256 + threadIdx.x;
        if (i < NB) out[1048576 + i] = disc[eid[i]];
        else if (i < NB + KNOW * DIM) out[1056768 + (i - NB)] = know[i - NB];
        return;
    }
    int w = (blockIdx.x * 256 + threadIdx.x) >> 6;   // wave id, 8192 total
    int lane = threadIdx.x & 63;
    int half = lane >> 5, l32 = lane & 31;
    int i = 2 * w + half;                            // output row 0..16383
    int r;
    long long obase;                                 // float offset
    if (i < NB) { r = sid[i];            obase = (long long)i * 64; }
    else        { r = STU + eid[i - NB]; obase = 524288 + (long long)(i - NB) * 64; }
    // h0 (f32) + B1 + B2 at dims {2*l32, 2*l32+1}
    long long rb2 = (long long)r * 32 + l32;         // float2 / u32 index
    float2 h0 = (r < STU) ? ((const float2*)stu)[rb2]
                          : ((const float2*)exer)[rb2 - (long long)STU * 32];
    unsigned b1 = ((const unsigned*)B1)[rb2];
    unsigned b2 = ((const unsigned*)B2)[rb2];
    float s0 = h0.x + __uint_as_float(b1 << 16) + __uint_as_float(b2 << 16);
    float s1 = h0.y + __uint_as_float(b1 & 0xffff0000u) + __uint_as_float(b2 & 0xffff0000u);
    // layer-3 gather over B2
    int st = off[r], en = off[r + 1];
    const unsigned* t32 = (const unsigned*)B2;
    float g0 = 0.f, g1 = 0.f;
    int deg = en - st;
    int degA = __shfl(deg, half ? 32 : 0, 64);       // not needed; use own bounds
    (void)degA;
    for (int k = st; k < en; k += 8) {
        int2 ev[8]; float wg[8];
#pragma unroll
        for (int q = 0; q < 8; q++) {
            int kk = k + q;
            int idx = (kk < en) ? kk : st;
            ev[q] = sedge[idx];
            wg[q] = (kk < en) ? __int_as_float(ev[q].y) : 0.f;
        }
        unsigned hv[8];
#pragma unroll
        for (int q = 0; q < 8; q++) hv[q] = t32[(size_t)ev[q].x * 32 + l32];
#pragma unroll
        for (int q = 0; q < 8; q++) {
            g0 += wg[q] * __uint_as_float(hv[q] << 16);
            g1 += wg[q] * __uint_as_float(hv[q] & 0xffff0000u);
        }
    }
    float2 o;
    o.x = 0.25f * (s0 + g0);
    o.y = 0.25f * (s1 + g1);
    ((float2*)out)[(obase >> 1) + l32] = o;
}

extern "C" void kernel_launch(void* const* d_in, const int* in_sizes, int n_in,
                              void* d_out, int out_size, void* d_ws, size_t ws_size,
                              hipStream_t stream) {
    const int*   sid  = (const int*)d_in[0];
    const int*   eid  = (const int*)d_in[1];
    const int*   erow = (const int*)d_in[3];
    const int*   ecol = (const int*)d_in[4];
    const float* eval = (const float*)d_in[5];
    const float* stu  = (const float*)d_in[6];
    const float* exer = (const float*)d_in[7];
    const float* disc = (const float*)d_in[8];
    const float* know = (const float*)d_in[9];
    float* out = (float*)d_out;

    char* ws = (char*)d_ws;
    bfu*  B0      = (bfu*) (ws);                          // 19,200,000
    bfu*  B1      = (bfu*) (ws + 19200000);               // 19,200,000
    bfu*  B2      = (bfu*) (ws + 38400000);               // 19,200,000
    int2* bedge   = (int2*)(ws + 57600000);               // 9,600,000 (bucket-sorted)
    int2* sedge   = (int2*)(ws + 67200000);               // 9,600,000 (row-sorted)
    int*  gcounts = (int*) (ws + 76800000);               // 600,064
    int*  gscan   = (int*) (ws + 77400064);               // 600,064
    int*  bsum    = (int*) (ws + 78000128);               // 2,560
    int*  bsumoff = (int*) (ws + 78002688);               // 2,560 (587 ints + pad)
    int*  off     = (int*) (ws + 78005248);               // 600,064 (ends ~78.6 MB)

    const int BLK = 256;
    long long n4 = ((long long)N_NODES * DIM) >> 2;
    int convGrid = (int)((n4 + BLK - 1) / BLK);
    int gatherGrid = N_NODES / RPB;                       // 9375 blocks
    int outGrid = OUTMAIN + (NB + KNOW * DIM + BLK - 1) / BLK;  // 2048 + 63

    // h0 -> bf16 table
    k_conv0<<<convGrid, BLK, 0, stream>>>(stu, exer, B0);

    // two-level counting sort (all writes dense); scan3 folded into place/sort
    k_count<<<PB, 1024, 0, stream>>>(erow, gcounts);
    k_scan1<<<NSB, 256, 0, stream>>>(gcounts, gscan, bsum);
    k_scan2<<<1, 1024, 0, stream>>>(bsum, bsumoff);
    k_place<<<PB, 1024, 0, stream>>>(erow, ecol, eval, gscan, bsumoff, bedge);
    k_sort <<<NBUCK, 512, 0, stream>>>(bsumoff, bedge, sedge, off);

    // layers 1,2
    k_gather16<<<gatherGrid, BLK, 0, stream>>>(off, sedge, B0, B1);
    k_gather16<<<gatherGrid, BLK, 0, stream>>>(off, sedge, B1, B2);

    // layer 3 + tails fused
    k_out<<<outGrid, BLK, 0, stream>>>(sid, eid, off, sedge, stu, exer, B1, B2,
                                       disc, know, out);
}

// Round 16
// 100.222 us; speedup vs baseline: 1.1747x; 1.0466x over previous
//
#include <hip/hip_runtime.h>

// LightGCN extractor, round 16: R15 base + conv0 fused into k_place as
// heterogeneous blocks (conv streams BW under place's latency-bound blocks).
//  - build: two-level counting sort, all global writes dense lane-consecutive
//  - gathers: 16 rows/block, records LDS-staged, 4 rows/wave, 16-lane groups
//  - out: 2 rows/wave half-wave split + fused tails
//  NOTE: float atomicAdd on __shared__ is a slow generic path (~8000cy, R7) - avoid.
//  NOTE: scatter stores only merge in the wave coalescer at issue time; L2 never
//        merges separately-issued stores (R1-R6 evidence) - LDS-staged dense
//        write-out everywhere.

#define STU 100000
#define EXER 50000
#define KNOW 123
#define DIM 64
#define N_NODES 150000
#define N_EDGES 1200000
#define NB 8192
#define BR 256                 // rows per bucket
#define NBUCK 586              // ceil(150000/256)
#define PB 256                 // partition blocks (== scan width, load-bearing)
#define EPB 4688               // ceil(N_EDGES/PB)
#define NSB 586                // scan blocks over NBUCK*PB = 150016
#define SCAP 3072              // max edges per bucket (mean 2048)
#define RPB 16                 // rows per gather block
#define RCAP 512               // record staging cap (sum of 16 Poisson(8) ~ 128)
#define OUTMAIN 2048           // out kernel: main blocks (8192 waves, 2 rows each)
#define CONVB 586              // conv blocks in fused place (4096 float4 each)

typedef unsigned short bfu;

__device__ __forceinline__ bfu f2bf(float f) {
    unsigned int u = __float_as_uint(f);
    unsigned int r = (u + 0x7FFFu + ((u >> 16) & 1u)) >> 16;   // RNE
    return (bfu)r;
}
__device__ __forceinline__ float bf2f(bfu h) {
    return __uint_as_float((unsigned int)h << 16);
}

// ---- bucket counts: gcounts[bucket*PB + block] ----
__global__ __launch_bounds__(1024) void k_count(const int* __restrict__ erow,
                                                int* __restrict__ gcounts) {
    __shared__ int cnt[NBUCK];
    for (int i = threadIdx.x; i < NBUCK; i += 1024) cnt[i] = 0;
    __syncthreads();
    int b = blockIdx.x;
    long long s = (long long)b * EPB;
    long long e = s + EPB; if (e > N_EDGES) e = N_EDGES;
    for (long long k = s + threadIdx.x; k < e; k += 1024)
        atomicAdd(&cnt[__builtin_nontemporal_load(&erow[k]) >> 8], 1);
    __syncthreads();
    for (int i = threadIdx.x; i < NBUCK; i += 1024) gcounts[i * PB + b] = cnt[i];
}

// ---- scan level 1: per-bucket exclusive scan of the 256 partition counts ----
__global__ void k_scan1(const int* __restrict__ gin, int* __restrict__ gout,
                        int* __restrict__ bsum) {
    __shared__ int s[256];
    int i = blockIdx.x * 256 + threadIdx.x;
    int v = gin[i];
    s[threadIdx.x] = v;
    __syncthreads();
    for (int o = 1; o < 256; o <<= 1) {
        int x = (threadIdx.x >= o) ? s[threadIdx.x - o] : 0;
        __syncthreads();
        s[threadIdx.x] += x;
        __syncthreads();
    }
    gout[i] = s[threadIdx.x] - v;
    if (threadIdx.x == 255) bsum[blockIdx.x] = s[255];
}

// ---- scan level 2: exclusive scan over bucket totals (+ sentinel) ----
__global__ void k_scan2(const int* __restrict__ bsum, int* __restrict__ bsumoff) {
    __shared__ int s[1024];
    int t = threadIdx.x;
    int v = (t < NSB) ? bsum[t] : 0;
    s[t] = v;
    __syncthreads();
    for (int o = 1; o < 1024; o <<= 1) {
        int x = (t >= o) ? s[t - o] : 0;
        __syncthreads();
        s[t] += x;
        __syncthreads();
    }
    if (t < NSB) bsumoff[t] = s[t] - v;
    if (t == NSB - 1) bsumoff[NSB] = s[t];   // == N_EDGES sentinel
}

// ---- fused: place (blocks 0..PB-1) | conv0 h0->bf16 (blocks PB..PB+CONVB-1) ----
__global__ __launch_bounds__(1024) void k_place_conv(const int* __restrict__ erow,
                                                     const int* __restrict__ ecol,
                                                     const float* __restrict__ eval,
                                                     const int* __restrict__ gscan,
                                                     const int* __restrict__ bsumoff,
                                                     int2* __restrict__ bedge,
                                                     const float* __restrict__ stu,
                                                     const float* __restrict__ exer,
                                                     bfu* __restrict__ b0) {
    if (blockIdx.x >= PB) {
        // conv part: 4 float4 per thread, coalesced
        long long cb = blockIdx.x - PB;
        long long n4 = ((long long)N_NODES * DIM) >> 2;
        long long stu4 = ((long long)STU * DIM) >> 2;
#pragma unroll
        for (int j = 0; j < 4; j++) {
            long long i = cb * 4096 + j * 1024 + threadIdx.x;
            if (i < n4) {
                float4 v = (i < stu4) ? ((const float4*)stu)[i]
                                      : ((const float4*)exer)[i - stu4];
                ushort4 o;
                o.x = f2bf(v.x); o.y = f2bf(v.y); o.z = f2bf(v.z); o.w = f2bf(v.w);
                ((ushort4*)b0)[i] = o;
            }
        }
        return;
    }
    __shared__ int2 staged[EPB];            // 37504 B
    __shared__ unsigned short sbkt[EPB];    // 9376 B
    __shared__ int lbase[NBUCK];
    __shared__ int lcur[NBUCK];
    __shared__ int gbase[NBUCK];
    __shared__ int stmp[1024];
    int b = blockIdx.x, tid = threadIdx.x;
    for (int i = tid; i < NBUCK; i += 1024) lcur[i] = 0;
    __syncthreads();
    long long s = (long long)b * EPB;
    long long e = s + EPB; if (e > N_EDGES) e = N_EDGES;
    int n = (int)(e - s);
    for (int k = tid; k < n; k += 1024)
        atomicAdd(&lcur[__builtin_nontemporal_load(&erow[s + k]) >> 8], 1);
    __syncthreads();
    int v = (tid < NBUCK) ? lcur[tid] : 0;
    stmp[tid] = v;
    __syncthreads();
    for (int o = 1; o < 1024; o <<= 1) {
        int x = (tid >= o) ? stmp[tid - o] : 0;
        __syncthreads();
        stmp[tid] += x;
        __syncthreads();
    }
    if (tid < NBUCK) { lbase[tid] = stmp[tid] - v; lcur[tid] = stmp[tid] - v; }
    for (int i = tid; i < NBUCK; i += 1024)
        gbase[i] = gscan[i * PB + b] + bsumoff[i];          // scan3 folded in
    __syncthreads();
    for (int k = tid; k < n; k += 1024) {
        int r = __builtin_nontemporal_load(&erow[s + k]);
        int c = __builtin_nontemporal_load(&ecol[s + k]);
        float vv = __builtin_nontemporal_load(&eval[s + k]);
        int bk = r >> 8;
        int p = atomicAdd(&lcur[bk], 1);
        staged[p] = make_int2((r & 255) | (c << 8), __float_as_int(vv));
        sbkt[p] = (unsigned short)bk;
    }
    __syncthreads();
    for (int t = tid; t < n; t += 1024) {
        int bk = sbkt[t];
        bedge[gbase[bk] + (t - lbase[bk])] = staged[t];
    }
}

// ---- per-bucket LDS counting sort by row -> row-sorted edges + off[] ----
__global__ __launch_bounds__(512) void k_sort(const int* __restrict__ bsumoff,
                                              const int2* __restrict__ bedge,
                                              int2* __restrict__ sedge,
                                              int* __restrict__ off) {
    __shared__ int2 st[SCAP];      // 24 KB
    __shared__ int2 st2[SCAP];     // 24 KB
    __shared__ int hist[BR];
    __shared__ int cur[BR];
    __shared__ int stmp[512];
    int b = blockIdx.x, tid = threadIdx.x;
    int s = bsumoff[b], e = bsumoff[b + 1];    // bucket bounds
    int n = e - s; if (n > SCAP) n = SCAP;     // statistically unreachable
    for (int i = tid; i < BR; i += 512) hist[i] = 0;
    __syncthreads();
    for (int t = tid; t < n; t += 512) {
        int2 ev = bedge[s + t];
        st[t] = ev;
        atomicAdd(&hist[ev.x & 255], 1);
    }
    __syncthreads();
    int v = (tid < BR) ? hist[tid] : 0;
    stmp[tid] = v;
    __syncthreads();
    for (int o = 1; o < 512; o <<= 1) {
        int x = (tid >= o) ? stmp[tid - o] : 0;
        __syncthreads();
        stmp[tid] += x;
        __syncthreads();
    }
    if (tid < BR) {
        int ex = stmp[tid] - v;
        cur[tid] = ex;
        off[b * BR + tid] = s + ex;    // global row offset
    }
    __syncthreads();
    for (int t = tid; t < n; t += 512) {
        int2 ev = st[t];
        int p = atomicAdd(&cur[ev.x & 255], 1);
        st2[p] = make_int2((unsigned)ev.x >> 8, ev.y);   // (col, valbits)
    }
    __syncthreads();
    for (int t = tid; t < n; t += 512) sedge[s + t] = st2[t];
}

// ---- gather layer: 16 rows/block, records LDS-staged, 4 rows/wave ----
__global__ __launch_bounds__(256) void k_gather16(const int* __restrict__ off,
                                                  const int2* __restrict__ sedge,
                                                  const bfu* __restrict__ h,
                                                  bfu* __restrict__ out) {
    __shared__ int2 rec[RCAP];
    __shared__ int soff[RPB + 1];
    int tid = threadIdx.x;
    int base = blockIdx.x * RPB;                 // 9375 blocks x 16 rows = 150000
    if (tid <= RPB) soff[tid] = off[base + tid];
    __syncthreads();
    int s0 = soff[0];
    int n = soff[RPB] - s0; if (n > RCAP) n = RCAP;   // unreachable
    for (int i = tid; i < n; i += 256) rec[i] = sedge[s0 + i];   // dense coalesced
    __syncthreads();

    int wv = tid >> 6, grp = (tid >> 4) & 3, l16 = tid & 15;
    int lr = wv * 4 + grp;                        // local row 0..15
    int rs = soff[lr] - s0, re = soff[lr + 1] - s0;
    const uint2* h2 = (const uint2*)h;            // row = 16 x uint2 (128B)
    float a0 = 0.f, a1 = 0.f, a2 = 0.f, a3 = 0.f;
    for (int k = rs; k < re; k += 8) {
        int2 ev[8]; float wg[8];
#pragma unroll
        for (int q = 0; q < 8; q++) {
            int idx = (k + q < re) ? (k + q) : rs;
            ev[q] = rec[idx];
            wg[q] = (k + q < re) ? __int_as_float(ev[q].y) : 0.f;
        }
        uint2 hv[8];
#pragma unroll
        for (int q = 0; q < 8; q++) hv[q] = h2[(size_t)ev[q].x * 16 + l16];
#pragma unroll
        for (int q = 0; q < 8; q++) {
            a0 += wg[q] * __uint_as_float(hv[q].x << 16);
            a1 += wg[q] * __uint_as_float(hv[q].x & 0xffff0000u);
            a2 += wg[q] * __uint_as_float(hv[q].y << 16);
            a3 += wg[q] * __uint_as_float(hv[q].y & 0xffff0000u);
        }
    }
    uint2 o;
    o.x = (unsigned)f2bf(a0) | ((unsigned)f2bf(a1) << 16);
    o.y = (unsigned)f2bf(a2) | ((unsigned)f2bf(a3) << 16);
    ((uint2*)out)[(size_t)(base + lr) * 16 + l16] = o;
}

// ---- fused outputs: layer-3 gather, 2 rows/wave (half-wave split) + tails ----
// out layout: [0,524288) student_ts | [524288,1048576) diff_ts
//             [1048576,1056768) disc | [1056768,1064640) know
__global__ __launch_bounds__(256) void k_out(const int* __restrict__ sid,
                                             const int* __restrict__ eid,
                                             const int* __restrict__ off,
                                             const int2* __restrict__ sedge,
                                             const float* __restrict__ stu,
                                             const float* __restrict__ exer,
                                             const bfu* __restrict__ B1,
                                             const bfu* __restrict__ B2,
                                             const float* __restrict__ disc,
                                             const float* __restrict__ know,
                                             float* __restrict__ out) {
    if (blockIdx.x >= OUTMAIN) {
        int i = (blockIdx.x - OUTMAIN) * 256 + threadIdx.x;
        if (i < NB) out[1048576 + i] = disc[eid[i]];
        else if (i < NB + KNOW * DIM) out[1056768 + (i - NB)] = know[i - NB];
        return;
    }
    int w = (blockIdx.x * 256 + threadIdx.x) >> 6;   // wave id, 8192 total
    int lane = threadIdx.x & 63;
    int half = lane >> 5, l32 = lane & 31;
    int i = 2 * w + half;                            // output row 0..16383
    int r;
    long long obase;                                 // float offset
    if (i < NB) { r = sid[i];            obase = (long long)i * 64; }
    else        { r = STU + eid[i - NB]; obase = 524288 + (long long)(i - NB) * 64; }
    long long rb2 = (long long)r * 32 + l32;         // float2 / u32 index
    float2 h0 = (r < STU) ? ((const float2*)stu)[rb2]
                          : ((const float2*)exer)[rb2 - (long long)STU * 32];
    unsigned b1 = ((const unsigned*)B1)[rb2];
    unsigned b2 = ((const unsigned*)B2)[rb2];
    float s0 = h0.x + __uint_as_float(b1 << 16) + __uint_as_float(b2 << 16);
    float s1 = h0.y + __uint_as_float(b1 & 0xffff0000u) + __uint_as_float(b2 & 0xffff0000u);
    int st = off[r], en = off[r + 1];
    const unsigned* t32 = (const unsigned*)B2;
    float g0 = 0.f, g1 = 0.f;
    for (int k = st; k < en; k += 8) {
        int2 ev[8]; float wg[8];
#pragma unroll
        for (int q = 0; q < 8; q++) {
            int kk = k + q;
            int idx = (kk < en) ? kk : st;
            ev[q] = sedge[idx];
            wg[q] = (kk < en) ? __int_as_float(ev[q].y) : 0.f;
        }
        unsigned hv[8];
#pragma unroll
        for (int q = 0; q < 8; q++) hv[q] = t32[(size_t)ev[q].x * 32 + l32];
#pragma unroll
        for (int q = 0; q < 8; q++) {
            g0 += wg[q] * __uint_as_float(hv[q] << 16);
            g1 += wg[q] * __uint_as_float(hv[q] & 0xffff0000u);
        }
    }
    float2 o;
    o.x = 0.25f * (s0 + g0);
    o.y = 0.25f * (s1 + g1);
    ((float2*)out)[(obase >> 1) + l32] = o;
}

extern "C" void kernel_launch(void* const* d_in, const int* in_sizes, int n_in,
                              void* d_out, int out_size, void* d_ws, size_t ws_size,
                              hipStream_t stream) {
    const int*   sid  = (const int*)d_in[0];
    const int*   eid  = (const int*)d_in[1];
    const int*   erow = (const int*)d_in[3];
    const int*   ecol = (const int*)d_in[4];
    const float* eval = (const float*)d_in[5];
    const float* stu  = (const float*)d_in[6];
    const float* exer = (const float*)d_in[7];
    const float* disc = (const float*)d_in[8];
    const float* know = (const float*)d_in[9];
    float* out = (float*)d_out;

    char* ws = (char*)d_ws;
    bfu*  B0      = (bfu*) (ws);                          // 19,200,000
    bfu*  B1      = (bfu*) (ws + 19200000);               // 19,200,000
    bfu*  B2      = (bfu*) (ws + 38400000);               // 19,200,000
    int2* bedge   = (int2*)(ws + 57600000);               // 9,600,000 (bucket-sorted)
    int2* sedge   = (int2*)(ws + 67200000);               // 9,600,000 (row-sorted)
    int*  gcounts = (int*) (ws + 76800000);               // 600,064
    int*  gscan   = (int*) (ws + 77400064);               // 600,064
    int*  bsum    = (int*) (ws + 78000128);               // 2,560
    int*  bsumoff = (int*) (ws + 78002688);               // 2,560 (587 ints + pad)
    int*  off     = (int*) (ws + 78005248);               // 600,064 (ends ~78.6 MB)

    const int BLK = 256;
    int gatherGrid = N_NODES / RPB;                       // 9375 blocks
    int outGrid = OUTMAIN + (NB + KNOW * DIM + BLK - 1) / BLK;  // 2048 + 63

    // two-level counting sort; conv0 fused into place as streaming blocks
    k_count<<<PB, 1024, 0, stream>>>(erow, gcounts);
    k_scan1<<<NSB, 256, 0, stream>>>(gcounts, gscan, bsum);
    k_scan2<<<1, 1024, 0, stream>>>(bsum, bsumoff);
    k_place_conv<<<PB + CONVB, 1024, 0, stream>>>(erow, ecol, eval, gscan, bsumoff,
                                                  bedge, stu, exer, B0);
    k_sort<<<NBUCK, 512, 0, stream>>>(bsumoff, bedge, sedge, off);

    // layers 1,2
    k_gather16<<<gatherGrid, BLK, 0, stream>>>(off, sedge, B0, B1);
    k_gather16<<<gatherGrid, BLK, 0, stream>>>(off, sedge, B1, B2);

    // layer 3 + tails fused
    k_out<<<outGrid, BLK, 0, stream>>>(sid, eid, off, sedge, stu, exer, B1, B2,
                                       disc, know, out);
}